// Round 2
// baseline (78.851 us; speedup 1.0000x reference)
//
#include <hip/hip_runtime.h>
#include <hip/hip_bf16.h>

// GaussianKernel: S[i][j] = exp(-||H1_i - H2_j||^2), N=8192, K=64, fp32 out.
// Round 2: prep kernel (fp32 -> swizzled bf16 hi/lo planes + norms in d_ws),
// main kernel stages via global_load_lds (async, width 16), swapped-operand
// MFMA so the epilogue stores float4 (nontemporal). Store-bound target.

typedef float  f32x4  __attribute__((ext_vector_type(4)));
typedef short  short8 __attribute__((ext_vector_type(8)));
typedef unsigned short ushort8 __attribute__((ext_vector_type(8)));

#define KD 64
#define TM 128
#define TN 128

#define PLANE_BYTES (8192u * 64u * 2u)               // 1 MiB per bf16 plane
#define OFF_N1  (4u * PLANE_BYTES)
#define OFF_N2  (4u * PLANE_BYTES + 8192u * 4u)
#define WS_NEED ((size_t)(4u * PLANE_BYTES + 2u * 8192u * 4u))

__device__ __forceinline__ unsigned short f2bf(float x) {
    __hip_bfloat16 h = __float2bfloat16(x);   // RNE
    unsigned short u;
    __builtin_memcpy(&u, &h, 2);
    return u;
}
__device__ __forceinline__ float bf2f(unsigned short u) {
    unsigned int v = ((unsigned int)u) << 16;
    float f;
    __builtin_memcpy(&f, &v, 4);
    return f;
}

__device__ __forceinline__ void gload_lds16(const void* g, void* l) {
    __builtin_amdgcn_global_load_lds(
        (const __attribute__((address_space(1))) unsigned char*)g,
        (__attribute__((address_space(3))) unsigned char*)l, 16, 0, 0);
}

// swizzled byte offset of (row-in-panel, 16B-chunk kc) inside a 16 KiB panel
__device__ __forceinline__ unsigned panel_off(unsigned rin, unsigned kcByte) {
    return (rin * 128u + kcByte) ^ ((rin & 7u) << 4);
}

// ---------------- prep: fp32 -> bf16 hi/lo planes (swizzled) + norms ----------------
__global__ __launch_bounds__(256) void gauss_prep(const float* __restrict__ H1,
                                                  const float* __restrict__ H2,
                                                  unsigned char* __restrict__ ws)
{
    const int cid   = blockIdx.x * 256 + threadIdx.x;   // 0..131071
    const int which = cid >> 16;                        // 0:H1 1:H2
    const int g     = cid & 65535;                      // chunk id within input
    const int row   = g >> 3;                           // 0..8191
    const int kc    = g & 7;                            // 16B chunk in row

    const float* src = which ? H2 : H1;
    const f32x4* p = (const f32x4*)(src + (size_t)g * 8);
    f32x4 v0 = p[0], v1 = p[1];

    ushort8 h, l;
    float s = 0.f;
    #pragma unroll
    for (int e = 0; e < 8; ++e) {
        float a = (e < 4) ? v0[e] : v1[e - 4];
        unsigned short hb = f2bf(a);
        h[e] = hb;
        l[e] = f2bf(a - bf2f(hb));
        s = fmaf(a, a, s);
    }
    // row norm: sum across the 8 chunk-threads (lanes differ in bits 0..2)
    s += __shfl_xor(s, 1);
    s += __shfl_xor(s, 2);
    s += __shfl_xor(s, 4);

    const unsigned rin = (unsigned)(row & 127);
    const size_t  pb   = (size_t)(row >> 7) * 16384u + panel_off(rin, (unsigned)kc * 16u);
    unsigned char* hi = ws + (which ? 2u * PLANE_BYTES : 0u) + pb;
    unsigned char* lo = ws + (which ? 3u * PLANE_BYTES : PLANE_BYTES) + pb;
    *(ushort8*)hi = h;
    *(ushort8*)lo = l;
    if (kc == 0)
        *(float*)(ws + (which ? OFF_N2 : OFF_N1) + (size_t)row * 4u) = s;
}

// ---------------- main ----------------
template <bool STAGED>
__global__ __launch_bounds__(256, 2) void gauss_main(const float* __restrict__ H1,
                                                     const float* __restrict__ H2,
                                                     const unsigned char* __restrict__ ws,
                                                     float* __restrict__ out, int n2dim)
{
    __shared__ __align__(16) unsigned char smem[65536];  // Ahi|Alo|Bhi|Blo, 16K each
    __shared__ __align__(16) float snrm[TM + TN];        // fallback path only

    const int t    = threadIdx.x;
    const int lane = t & 63, w = t >> 6;
    const int wr = w >> 1, wc = w & 1;
    const int lr = lane & 15, kb = lane >> 4;
    const int r4 = kb * 4;
    const int row0 = blockIdx.y * TM;
    const int col0 = blockIdx.x * TN;

    float n1v[4];
    f32x4 n2v[4];

    if (STAGED) {
        const float* nrm1 = (const float*)(ws + OFF_N1);
        const float* nrm2 = (const float*)(ws + OFF_N2);
        #pragma unroll
        for (int fr = 0; fr < 4; ++fr)
            n1v[fr] = nrm1[row0 + wr * 64 + fr * 16 + lr];
        #pragma unroll
        for (int fc = 0; fc < 4; ++fc)
            n2v[fc] = *(const f32x4*)(nrm2 + col0 + wc * 64 + fc * 16 + r4);

        const size_t pa = (size_t)(row0 >> 7) * 16384u;
        const size_t pb = (size_t)(col0 >> 7) * 16384u;
        #pragma unroll
        for (int it = 0; it < 16; ++it) {
            const int region = it >> 2;                 // 0 Ahi, 1 Alo, 2 Bhi, 3 Blo
            const size_t panel = (region < 2) ? pa : pb;
            const unsigned char* gsrc = ws + (size_t)region * PLANE_BYTES + panel
                                      + (size_t)(it & 3) * 4096u + (size_t)t * 16u;
            gload_lds16(gsrc, smem + it * 4096 + w * 1024);
        }
    } else {
        // fallback: convert in-kernel into the same swizzled LDS image + fused norms
        #pragma unroll
        for (int side = 0; side < 2; ++side) {
            const float* src = side ? (H2 + (size_t)col0 * KD) : (H1 + (size_t)row0 * KD);
            unsigned char* hi = (unsigned char*)smem + (side ? 32768 : 0);
            unsigned char* lo = hi + 16384;
            #pragma unroll
            for (int i = 0; i < 4; ++i) {
                int g   = i * 256 + t;
                int row = g >> 3;
                int kc  = g & 7;                         // == t & 7
                const f32x4* p = (const f32x4*)(src + (size_t)g * 8);
                f32x4 v0 = p[0], v1 = p[1];
                ushort8 h, l;
                float s = 0.f;
                #pragma unroll
                for (int e = 0; e < 8; ++e) {
                    float a = (e < 4) ? v0[e] : v1[e - 4];
                    unsigned short hb = f2bf(a);
                    h[e] = hb;
                    l[e] = f2bf(a - bf2f(hb));
                    s = fmaf(a, a, s);
                }
                s += __shfl_xor(s, 1);
                s += __shfl_xor(s, 2);
                s += __shfl_xor(s, 4);
                unsigned off = panel_off((unsigned)row, (unsigned)kc * 16u);
                *(ushort8*)(hi + off) = h;
                *(ushort8*)(lo + off) = l;
                if (kc == 0) snrm[side * TM + row] = s;
            }
        }
    }
    __syncthreads();

    if (!STAGED) {
        #pragma unroll
        for (int fr = 0; fr < 4; ++fr)
            n1v[fr] = snrm[wr * 64 + fr * 16 + lr];
        #pragma unroll
        for (int fc = 0; fc < 4; ++fc)
            n2v[fc] = *(const f32x4*)&snrm[TM + wc * 64 + fc * 16 + r4];
    }

    const unsigned char* sAhi = smem;
    const unsigned char* sAlo = smem + 16384;
    const unsigned char* sBhi = smem + 32768;
    const unsigned char* sBlo = smem + 49152;

    f32x4 acc[4][4];
    #pragma unroll
    for (int a = 0; a < 4; ++a)
        #pragma unroll
        for (int b = 0; b < 4; ++b)
            acc[a][b] = (f32x4){0.f, 0.f, 0.f, 0.f};

    #pragma unroll
    for (int ks = 0; ks < 2; ++ks) {
        const unsigned kByte = (unsigned)(ks * 64 + kb * 16);
        short8 ah[4], al[4];
        #pragma unroll
        for (int fr = 0; fr < 4; ++fr) {
            const unsigned rowa = (unsigned)(wr * 64 + fr * 16 + lr);
            const unsigned off  = panel_off(rowa, kByte);
            ah[fr] = *(const short8*)(sAhi + off);
            al[fr] = *(const short8*)(sAlo + off);
        }
        #pragma unroll
        for (int fc = 0; fc < 4; ++fc) {
            const unsigned rowb = (unsigned)(wc * 64 + fc * 16 + lr);
            const unsigned off  = panel_off(rowb, kByte);
            short8 bh = *(const short8*)(sBhi + off);
            short8 bl = *(const short8*)(sBlo + off);
            #pragma unroll
            for (int fr = 0; fr < 4; ++fr) {
                // swapped operands: D row-dim (j) <- H2 rows (out cols),
                //                   D col-dim (lane&15) <- H1 rows (out rows)
                acc[fr][fc] = __builtin_amdgcn_mfma_f32_16x16x32_bf16(bh, ah[fr], acc[fr][fc], 0, 0, 0);
                acc[fr][fc] = __builtin_amdgcn_mfma_f32_16x16x32_bf16(bl, ah[fr], acc[fr][fc], 0, 0, 0);
                acc[fr][fc] = __builtin_amdgcn_mfma_f32_16x16x32_bf16(bh, al[fr], acc[fr][fc], 0, 0, 0);
            }
        }
    }

    // epilogue: out = exp(-(n1 + n2 - 2*dot)), float4 nontemporal stores
    #pragma unroll
    for (int fr = 0; fr < 4; ++fr) {
        const int grow = row0 + wr * 64 + fr * 16 + lr;
        float* orow = out + (size_t)grow * (size_t)n2dim + (col0 + wc * 64 + r4);
        #pragma unroll
        for (int fc = 0; fc < 4; ++fc) {
            f32x4 cst;
            #pragma unroll
            for (int j = 0; j < 4; ++j) {
                float d2 = fmaf(-2.0f, acc[fr][fc][j], n1v[fr] + n2v[fc][j]);
                cst[j] = __expf(-d2);
            }
            __builtin_nontemporal_store(cst, (f32x4*)(orow + fc * 16));
        }
    }
}

extern "C" void kernel_launch(void* const* d_in, const int* in_sizes, int n_in,
                              void* d_out, int out_size, void* d_ws, size_t ws_size,
                              hipStream_t stream) {
    const float* H1 = (const float*)d_in[0];
    const float* H2 = (const float*)d_in[1];
    float* out = (float*)d_out;
    const int n1 = in_sizes[0] / KD;   // 8192
    const int n2 = in_sizes[1] / KD;   // 8192
    dim3 grid(n2 / TN, n1 / TM);

    if (ws_size >= WS_NEED) {
        gauss_prep<<<dim3(512), dim3(256), 0, stream>>>(H1, H2, (unsigned char*)d_ws);
        gauss_main<true><<<grid, dim3(256), 0, stream>>>(H1, H2, (const unsigned char*)d_ws, out, n2);
    } else {
        gauss_main<false><<<grid, dim3(256), 0, stream>>>(H1, H2, nullptr, out, n2);
    }
}

// Round 3
// 61.898 us; speedup vs baseline: 1.2739x; 1.2739x over previous
//
#include <hip/hip_runtime.h>
#include <hip/hip_bf16.h>

// GaussianKernel: S[i][j] = exp(-||H1_i - H2_j||^2), N=8192, K=64, fp32 out.
// Round 3: single kernel (revert round-2 prep + nontemporal stores, the
// regression suspects). Keep swapped-operand MFMA -> float4 regular stores.
// 512-thread blocks: 16 waves/CU (4/SIMD) for store-latency hiding.
// Split-bf16 (hi/lo planes, 3 mfma passes) for fp32-grade accuracy.

typedef float  f32x4  __attribute__((ext_vector_type(4)));
typedef short  short8 __attribute__((ext_vector_type(8)));
typedef unsigned short ushort8 __attribute__((ext_vector_type(8)));

#define KD 64
#define TM 128
#define TN 128

__device__ __forceinline__ unsigned short f2bf(float x) {
    __hip_bfloat16 h = __float2bfloat16(x);   // RNE
    unsigned short u;
    __builtin_memcpy(&u, &h, 2);
    return u;
}
__device__ __forceinline__ float bf2f(unsigned short u) {
    unsigned int v = ((unsigned int)u) << 16;
    float f;
    __builtin_memcpy(&f, &v, 4);
    return f;
}

// swizzled byte offset of (row, 16B-chunk byte offset) in a [128][64]-bf16 panel
__device__ __forceinline__ unsigned panel_off(unsigned row, unsigned kcByte) {
    return (row * 128u + kcByte) ^ ((row & 7u) << 4);
}

__global__ __launch_bounds__(512, 4) void gauss_mfma(
    const float* __restrict__ H1, const float* __restrict__ H2,
    float* __restrict__ out, int N2)
{
    __shared__ __align__(16) unsigned char sAhi[TM * KD * 2];   // 16 KiB each
    __shared__ __align__(16) unsigned char sAlo[TM * KD * 2];
    __shared__ __align__(16) unsigned char sBhi[TN * KD * 2];
    __shared__ __align__(16) unsigned char sBlo[TN * KD * 2];
    __shared__ __align__(16) float snrm[TM + TN];

    const int t    = threadIdx.x;        // 0..511
    const int lane = t & 63, w = t >> 6; // 8 waves
    const int wr = w >> 2, wc = w & 3;   // wave grid 2 x 4
    const int lr = lane & 15;            // output-row index within fragment
    const int kb = lane >> 4;            // k-block 0..3 / col-group
    const int r4 = kb * 4;
    const int row0 = blockIdx.y * TM;
    const int col0 = blockIdx.x * TN;

    // ---- stage: fp32 -> bf16 hi/lo planes (swizzled) + fused row norms ----
    #pragma unroll
    for (int side = 0; side < 2; ++side) {
        const float* src = side ? (H2 + (size_t)col0 * KD)
                                : (H1 + (size_t)row0 * KD);
        unsigned char* hi = side ? sBhi : sAhi;
        unsigned char* lo = side ? sBlo : sAlo;
        #pragma unroll
        for (int i = 0; i < 2; ++i) {
            int g   = i * 512 + t;               // 16B chunk id, 0..1023
            int row = g >> 3;                    // 0..127
            int kc  = g & 7;                     // == t & 7
            const f32x4* p = (const f32x4*)(src + (size_t)g * 8);
            f32x4 v0 = p[0], v1 = p[1];
            ushort8 h, l;
            float s = 0.f;
            #pragma unroll
            for (int e = 0; e < 8; ++e) {
                float a = (e < 4) ? v0[e] : v1[e - 4];
                unsigned short hb = f2bf(a);
                h[e] = hb;
                l[e] = f2bf(a - bf2f(hb));
                s = fmaf(a, a, s);
            }
            // row norm: reduce across the 8 chunk-threads of this row
            s += __shfl_xor(s, 1);
            s += __shfl_xor(s, 2);
            s += __shfl_xor(s, 4);
            unsigned off = panel_off((unsigned)row, (unsigned)kc * 16u);
            *(ushort8*)(hi + off) = h;
            *(ushort8*)(lo + off) = l;
            if (kc == 0) snrm[side * TM + row] = s;
        }
    }
    __syncthreads();

    // ---- per-wave norms into registers ----
    float n1v[4];
    f32x4 n2v[2];
    #pragma unroll
    for (int fr = 0; fr < 4; ++fr)
        n1v[fr] = snrm[wr * 64 + fr * 16 + lr];
    #pragma unroll
    for (int fc = 0; fc < 2; ++fc)
        n2v[fc] = *(const f32x4*)&snrm[TM + wc * 32 + fc * 16 + r4];

    // ---- MFMA: each wave owns 64x32 of the 128x128 tile ----
    f32x4 acc[4][2];
    #pragma unroll
    for (int a = 0; a < 4; ++a)
        #pragma unroll
        for (int b = 0; b < 2; ++b)
            acc[a][b] = (f32x4){0.f, 0.f, 0.f, 0.f};

    #pragma unroll
    for (int ks = 0; ks < 2; ++ks) {
        const unsigned kByte = (unsigned)(ks * 64 + kb * 16);
        short8 ah[4], al[4];
        #pragma unroll
        for (int fr = 0; fr < 4; ++fr) {
            const unsigned off = panel_off((unsigned)(wr * 64 + fr * 16 + lr), kByte);
            ah[fr] = *(const short8*)(sAhi + off);
            al[fr] = *(const short8*)(sAlo + off);
        }
        #pragma unroll
        for (int fc = 0; fc < 2; ++fc) {
            const unsigned off = panel_off((unsigned)(wc * 32 + fc * 16 + lr), kByte);
            short8 bh = *(const short8*)(sBhi + off);
            short8 bl = *(const short8*)(sBlo + off);
            #pragma unroll
            for (int fr = 0; fr < 4; ++fr) {
                // swapped operands: D's j-dim walks output COLUMNS (H2 rows),
                // D's lane&15 dim walks output ROWS (H1 rows).
                acc[fr][fc] = __builtin_amdgcn_mfma_f32_16x16x32_bf16(bh, ah[fr], acc[fr][fc], 0, 0, 0);
                acc[fr][fc] = __builtin_amdgcn_mfma_f32_16x16x32_bf16(bl, ah[fr], acc[fr][fc], 0, 0, 0);
                acc[fr][fc] = __builtin_amdgcn_mfma_f32_16x16x32_bf16(bh, al[fr], acc[fr][fc], 0, 0, 0);
            }
        }
    }

    // ---- epilogue: out = exp(-(n1 + n2 - 2*dot)), float4 regular stores ----
    #pragma unroll
    for (int fr = 0; fr < 4; ++fr) {
        const int grow = row0 + wr * 64 + fr * 16 + lr;
        float* orow = out + (size_t)grow * (size_t)N2 + (col0 + wc * 32 + r4);
        #pragma unroll
        for (int fc = 0; fc < 2; ++fc) {
            f32x4 cst;
            #pragma unroll
            for (int j = 0; j < 4; ++j) {
                float d2 = fmaf(-2.0f, acc[fr][fc][j], n1v[fr] + n2v[fc][j]);
                cst[j] = __expf(-d2);
            }
            *(f32x4*)(orow + fc * 16) = cst;
        }
    }
}

extern "C" void kernel_launch(void* const* d_in, const int* in_sizes, int n_in,
                              void* d_out, int out_size, void* d_ws, size_t ws_size,
                              hipStream_t stream) {
    const float* H1 = (const float*)d_in[0];
    const float* H2 = (const float*)d_in[1];
    float* out = (float*)d_out;
    const int n1 = in_sizes[0] / KD;   // 8192
    const int n2 = in_sizes[1] / KD;   // 8192
    dim3 grid(n2 / TN, n1 / TM);
    gauss_mfma<<<grid, dim3(512), 0, stream>>>(H1, H2, out, n2);
}